// Round 16
// baseline (173.570 us; speedup 1.0000x reference)
//
#include <hip/hip_runtime.h>
#include <hip/hip_bf16.h>
#include <hip/hip_fp16.h>
#include <math.h>

// Problem constants
#define NL 4096     // L patches
#define NQ 4096     // HS*WS pixels
#define SCALE 10.0f

typedef __bf16 bf16x8 __attribute__((ext_vector_type(8)));
typedef float  f32x4  __attribute__((ext_vector_type(4)));
typedef float  f32x4u __attribute__((ext_vector_type(4), aligned(4)));  // 4B-aligned vec load

#define GLOAD_LDS16(gp, lp)                                                        \
    __builtin_amdgcn_global_load_lds((const __attribute__((address_space(1))) void*)(gp), \
                                     (__attribute__((address_space(3))) void*)(lp), \
                                     16, 0, 0)

// ---------------------------------------------------------------------------
// K1: fused double-diagonal pass, 16-l blocks, TRANSPOSED output Ft[q][l].
// Generalization of the round-13-verified 4-wb structure: window = 18 rows
// per d shared by 16 l (1.13 rows/output vs 1.5), masks identical formulas
// (row-invalid reduces to i==0 @wb0==0 for h2<0, i==15 @wb0==48 for h2>63).
// Output via LDS subtile transpose; each lane stores a full 64B Ft row chunk.
// ---------------------------------------------------------------------------
__global__ __launch_bounds__(256) void fuseDT(const float* __restrict__ S,
                                              float* __restrict__ Ft) {
    int bx = blockIdx.x;                      // 0..255 l-groups
    int lg = (bx & 7) * 32 + (bx >> 3);       // bijective XCD chunking (256%8==0)
    int l0 = lg * 16;
    int hb = l0 >> 6;
    int wb0 = l0 & 63;                        // 0,16,32,48
    int tid = threadIdx.x, lane = tid & 63;
    int qbase = blockIdx.y * 1024;
    int q0 = qbase + tid * 4;
    int hs = q0 >> 6, ws0 = q0 & 63;

    f32x4 z4 = {0.f, 0.f, 0.f, 0.f};
    f32x4 acc[16];
    #pragma unroll
    for (int i = 0; i < 16; ++i) acc[i] = z4;

    #pragma unroll
    for (int d = 0; d < 3; ++d) {
        int h2 = hb + d - 1;
        int rowbase;
        if (h2 >= 0 && h2 <= 63) rowbase = h2 * 64 + wb0;
        else if (h2 < 0)         rowbase = 4031 + wb0;
        else                     rowbase = 1 + wb0;
        bool skip0  = (h2 < 0)  && (wb0 == 0);    // l index i==0 invalid
        bool skip15 = (h2 > 63) && (wb0 == 48);   // l index i==15 invalid

        int s2 = hs + d - 1;
        bool cw = (s2 < 0) || (s2 > 63);
        int colb = cw ? ((s2 < 0 ? 4031 : 1) + ws0) : (q0 + (d - 1) * 64);
        int cb = cw ? colb - 1 : colb;

        // 18-row window loads (row-guarded)
        f32x4 v[18], v2[18];
        #pragma unroll
        for (int r = 0; r < 18; ++r) {
            int rr = rowbase - 1 + r;
            v[r] = z4;
            if (rr >= 0 && rr < 4096)
                v[r] = *(const f32x4u*)(S + (size_t)rr * 4096 + cb);
        }
        if (cw) {
            #pragma unroll
            for (int r = 0; r < 18; ++r) {
                int rr = rowbase - 1 + r;
                v2[r] = z4;
                if (rr >= 0 && rr < 4096)
                    v2[r] = *(const f32x4u*)(S + (size_t)rr * 4096 + colb + 1);
            }
        }

        // cross-lane shifted elements (interior path)
        float lm[16], rm[16];
        #pragma unroll
        for (int r = 0; r < 16; ++r) lm[r] = __shfl_up(v[r][3], 1);
        #pragma unroll
        for (int r = 0; r < 16; ++r) rm[r] = __shfl_down(v[r + 2][0], 1);
        if (!cw) {
            if (lane == 0 || colb == 0) {
                #pragma unroll
                for (int r = 0; r < 16; ++r) {
                    int rr = rowbase - 1 + r;
                    lm[r] = (colb > 0 && rr >= 0 && rr < 4096)
                            ? S[(size_t)rr * 4096 + colb - 1] : 0.f;
                }
            }
            if (lane == 63 || colb + 4 >= 4096) {
                #pragma unroll
                for (int r = 0; r < 16; ++r) {
                    int rr = rowbase + 1 + r;
                    rm[r] = (colb + 4 < 4096 && rr >= 0 && rr < 4096)
                            ? S[(size_t)rr * 4096 + colb + 4] : 0.f;
                }
            }
        }

        #pragma unroll
        for (int i = 0; i < 16; ++i) {
            f32x4 ti;
            if (!cw) {
                f32x4 Lv = { lm[i], v[i][0], v[i][1], v[i][2] };
                f32x4 Cv = v[i + 1];
                f32x4 Rv = { v[i + 2][1], v[i + 2][2], v[i + 2][3], rm[i] };
                ti = Lv + Cv + Rv;
            } else {
                f32x4 Lv = v[i];                                              // colb-1..+2
                f32x4 Cv = { v[i+1][1], v[i+1][2], v[i+1][3], v2[i+1][2] };   // colb..+3
                f32x4 Rv = v2[i + 2];                                         // colb+1..+4
                ti = Lv + Cv + Rv;
                if (s2 < 0 && ws0 == 0)   ti[0] = 0.f;
                if (s2 > 63 && ws0 == 60) ti[3] = 0.f;
            }
            bool skip = (i == 0 && skip0) || (i == 15 && skip15);
            if (!skip) acc[i] += ti;
        }
    }

    // LDS transpose: 4 subtiles of 256 q; out: lane -> one q row, 64B chunk.
    __shared__ float T[16][260];
    int sg = tid >> 6;
    #pragma unroll
    for (int st = 0; st < 4; ++st) {
        if (sg == st) {
            int qc = (tid & 63) * 4;
            #pragma unroll
            for (int i = 0; i < 16; ++i)
                *(f32x4*)&T[i][qc] = acc[i];
        }
        __syncthreads();
        {
            float tmp[16];
            #pragma unroll
            for (int i = 0; i < 16; ++i) tmp[i] = T[i][tid];
            float* dst = Ft + (size_t)(qbase + st * 256 + tid) * 4096 + l0;
            #pragma unroll
            for (int i2 = 0; i2 < 4; ++i2) {
                f32x4 o = { tmp[i2*4], tmp[i2*4+1], tmp[i2*4+2], tmp[i2*4+3] };
                *(f32x4*)&dst[i2 * 4] = o;
            }
        }
        __syncthreads();
    }
}

// ---------------------------------------------------------------------------
// S: single-pass masked row softmax (round-6 verified). Block = one q row of
// Ft[q][l] (16 KB contiguous). Register-caches 16 values/thread; writes
// Pt[q][l] bf16. Masked entries contribute exp(-m) (matches reference).
// ---------------------------------------------------------------------------
__global__ __launch_bounds__(256) void rowSoftmax(const float* __restrict__ Ft,
                                                  const float* __restrict__ mm,
                                                  __hip_bfloat16* __restrict__ Pt) {
    int q = blockIdx.x;
    int tid = threadIdx.x, lane = tid & 63, w = tid >> 6;
    const float4* Fr = (const float4*)(Ft + (size_t)q * 4096);
    const float4* M4 = (const float4*)mm;
    __shared__ float red[4];

    float sv[4][4], mv[4][4];
    float m = -1e30f;
    #pragma unroll
    for (int c = 0; c < 4; ++c) {
        int i = c * 256 + tid;
        float4 f = Fr[i], g = M4[i];
        #pragma unroll
        for (int j = 0; j < 4; ++j) {
            float s = ((const float*)&f)[j] * ((const float*)&g)[j] * SCALE;
            sv[c][j] = s;
            mv[c][j] = ((const float*)&g)[j];
            m = fmaxf(m, s);
        }
    }
    #pragma unroll
    for (int off = 32; off >= 1; off >>= 1) m = fmaxf(m, __shfl_xor(m, off));
    if (lane == 0) red[w] = m;
    __syncthreads();
    m = fmaxf(fmaxf(red[0], red[1]), fmaxf(red[2], red[3]));
    __syncthreads();

    float sum = 0.f;
    #pragma unroll
    for (int c = 0; c < 4; ++c)
        #pragma unroll
        for (int j = 0; j < 4; ++j) sum += __expf(sv[c][j] - m);
    #pragma unroll
    for (int off = 32; off >= 1; off >>= 1) sum += __shfl_xor(sum, off);
    if (lane == 0) red[w] = sum;
    __syncthreads();
    float inv = 1.0f / (red[0] + red[1] + red[2] + red[3]);

    #pragma unroll
    for (int c = 0; c < 4; ++c) {
        int i = c * 256 + tid;
        __hip_bfloat16 ob[4];
        #pragma unroll
        for (int j = 0; j < 4; ++j)
            ob[j] = (__hip_bfloat16)(mv[c][j] * __expf(sv[c][j] - m) * inv);
        *(uint2*)(Pt + (size_t)q * 4096 + i * 4) = *(const uint2*)ob;
    }
}

// ---------------------------------------------------------------------------
// Wt: transpose + convert raw_w [k][ck] fp32 -> Wt [n][k] bf16, with the
// GEMM N-dim permuted as n = kyx*64 + c (so scatterD reads Mo coalesced).
// ---------------------------------------------------------------------------
__global__ __launch_bounds__(256) void transW(const float* __restrict__ Wsrc,
                                              __hip_bfloat16* __restrict__ Wt) {
    __shared__ float T[64][65];
    int nt = blockIdx.x, kt = blockIdx.y;
    int c = threadIdx.x & 63;
    #pragma unroll
    for (int p = 0; p < 16; ++p) {
        int r = p * 4 + (threadIdx.x >> 6);
        T[r][c] = Wsrc[(size_t)(kt * 64 + r) * 1024 + nt * 64 + c];
    }
    __syncthreads();
    #pragma unroll
    for (int p = 0; p < 16; ++p) {
        int r = p * 4 + (threadIdx.x >> 6);   // r = ck_local; ck = nt*64 + r
        int n_new = (r & 15) * 64 + nt * 4 + (r >> 4);   // kyx*64 + c_chan
        Wt[(size_t)n_new * 4096 + kt * 64 + c] = (__hip_bfloat16)T[c][r];
    }
}

// ---------------------------------------------------------------------------
// Wc prep: conv weight [co][ci][3][3] fp32 -> Wc[kyx][co][ci] bf16.
// ---------------------------------------------------------------------------
__global__ void transWc(const float* __restrict__ Wsrc, __hip_bfloat16* __restrict__ Wd) {
    int t = blockIdx.x * 256 + threadIdx.x;   // kyx*4096 + co*64 + ci
    int kyx = t >> 12;
    int co = (t >> 6) & 63;
    int ci = t & 63;
    Wd[t] = (__hip_bfloat16)Wsrc[co * 576 + ci * 9 + kyx];
}

// ---------------------------------------------------------------------------
// zeroB: zero the borders of padded NHWC buffers Xp and Y1p (replaces the
// two 2MB memsets; interiors are fully written by scatterD / convMfma<0>).
// ---------------------------------------------------------------------------
__global__ void zeroB(__hip_bfloat16* __restrict__ Xp, __hip_bfloat16* __restrict__ Y1p) {
    int p = blockIdx.x;        // 0..515 border pixel index
    int c = threadIdx.x;       // 0..63
    int y, x;
    if (p < 130)      { y = 0;   x = p; }
    else if (p < 260) { y = 129; x = p - 130; }
    else if (p < 388) { y = p - 260 + 1; x = 0; }
    else              { y = p - 388 + 1; x = 129; }
    size_t off = ((size_t)y * 130 + x) * 64 + c;
    Xp[off]  = (__hip_bfloat16)0.f;
    Y1p[off] = (__hip_bfloat16)0.f;
}

// ---------------------------------------------------------------------------
// K4: bf16 MFMA GEMM, K-SPLIT x4, fp16 C quarters. Grid 1024 = 4 blocks/CU;
// bn fastest within XCD chunk; both-sides XOR swizzle (conflicts=0 verified).
// ---------------------------------------------------------------------------
__global__ __launch_bounds__(256) void gemmMfmaK(const __hip_bfloat16* __restrict__ Ab,
                                                 const __hip_bfloat16* __restrict__ Bb,
                                                 __half* __restrict__ C0,
                                                 __half* __restrict__ C1,
                                                 __half* __restrict__ C2,
                                                 __half* __restrict__ C3) {
    __shared__ __align__(16) __hip_bfloat16 As[2][128][32];  // 16 KiB
    __shared__ __align__(16) __hip_bfloat16 Bs[2][128][32];  // 16 KiB
    int lin = blockIdx.x;
    int wid = (lin & 7) * 128 + (lin >> 3);   // bijective XCD chunking (1024%8==0)
    int bz = wid >> 8;                         // 0..3 K-quarter
    int r5 = wid & 255;
    int bn = r5 & 7;                           // bn fastest -> B-panel L2 reuse
    int bm = r5 >> 3;
    int bm0 = bm * 128, bn0 = bn * 128;
    size_t kbase = (size_t)bz * 1024;
    __half* Cm = (bz == 0) ? C0 : (bz == 1) ? C1 : (bz == 2) ? C2 : C3;

    int tid = threadIdx.x;
    int lane = tid & 63, w = tid >> 6;
    int wm = (w >> 1) * 64, wn = (w & 1) * 64;

    int srow = w * 32 + (lane >> 2);
    int scol = (((lane & 3) ^ ((lane >> 3) & 3))) * 8;   // swizzled source col
    const __hip_bfloat16* ga0 = Ab + (size_t)(bm0 + srow) * 4096 + kbase + scol;
    const __hip_bfloat16* ga1 = Ab + (size_t)(bm0 + srow + 16) * 4096 + kbase + scol;
    const __hip_bfloat16* gb0 = Bb + (size_t)(bn0 + srow) * 4096 + kbase + scol;
    const __hip_bfloat16* gb1 = Bb + (size_t)(bn0 + srow + 16) * 4096 + kbase + scol;

    f32x4 acc[4][4] = {};
    int fm = lane & 15;
    int fkz = (((lane >> 4) ^ ((lane >> 1) & 3))) * 8;   // swizzled k-offset

    GLOAD_LDS16(ga0, &As[0][w * 32][0]);
    GLOAD_LDS16(ga1, &As[0][w * 32 + 16][0]);
    GLOAD_LDS16(gb0, &Bs[0][w * 32][0]);
    GLOAD_LDS16(gb1, &Bs[0][w * 32 + 16][0]);
    __syncthreads();

    int buf = 0;
    for (int t = 0; t < 32; ++t) {
        if (t + 1 < 32) {
            int k0 = (t + 1) * 32;
            GLOAD_LDS16(ga0 + k0, &As[buf ^ 1][w * 32][0]);
            GLOAD_LDS16(ga1 + k0, &As[buf ^ 1][w * 32 + 16][0]);
            GLOAD_LDS16(gb0 + k0, &Bs[buf ^ 1][w * 32][0]);
            GLOAD_LDS16(gb1 + k0, &Bs[buf ^ 1][w * 32 + 16][0]);
        }
        bf16x8 af[4], bfr[4];
        #pragma unroll
        for (int i = 0; i < 4; ++i)
            af[i] = *(const bf16x8*)&As[buf][wm + i * 16 + fm][fkz];
        #pragma unroll
        for (int j = 0; j < 4; ++j)
            bfr[j] = *(const bf16x8*)&Bs[buf][wn + j * 16 + fm][fkz];
        #pragma unroll
        for (int i = 0; i < 4; ++i)
            #pragma unroll
            for (int j = 0; j < 4; ++j)
                acc[i][j] = __builtin_amdgcn_mfma_f32_16x16x32_bf16(af[i], bfr[j], acc[i][j], 0, 0, 0);
        __syncthreads();
        buf ^= 1;
    }

    // D mapping: col = lane&15, row = (lane>>4)*4 + reg  [HW-verified]
    #pragma unroll
    for (int i = 0; i < 4; ++i) {
        #pragma unroll
        for (int j = 0; j < 4; ++j) {
            int row = bm0 + wm + i * 16 + (lane >> 4) * 4;
            int col = bn0 + wn + j * 16 + (lane & 15);
            #pragma unroll
            for (int r = 0; r < 4; ++r)
                Cm[(size_t)(row + r) * 1024 + col] = __float2half(acc[i][j][r]);
        }
    }
}

// ---------------------------------------------------------------------------
// K5: transposed-conv gather + /4, summing the four fp16 K-quarters ->
// padded NHWC bf16 Xp[130][130][64] (interior only; borders via zeroB).
// ---------------------------------------------------------------------------
__global__ void scatterD(const __half* __restrict__ Mo, const __half* __restrict__ Mo2,
                         const __half* __restrict__ Mo3, const __half* __restrict__ Mo4,
                         __hip_bfloat16* __restrict__ Xp) {
    int c = threadIdx.x & 63;
    int pix = blockIdx.x * 4 + (threadIdx.x >> 6);
    int ox = pix & 127, oy = pix >> 7;
    float acc = 0.f;
    #pragma unroll
    for (int ky = 0; ky < 4; ++ky) {
        int ty = oy + 1 - ky;
        if (ty & 1) continue;
        int iy = ty >> 1;
        if (iy < 0 || iy >= 64) continue;
        #pragma unroll
        for (int kx = 0; kx < 4; ++kx) {
            int txx = ox + 1 - kx;
            if (txx & 1) continue;
            int ix = txx >> 1;
            if (ix < 0 || ix >= 64) continue;
            size_t off = (size_t)(iy * 64 + ix) * 1024 + (ky * 4 + kx) * 64 + c;
            acc += (__half2float(Mo[off]) + __half2float(Mo2[off]))
                 + (__half2float(Mo3[off]) + __half2float(Mo4[off]));
        }
    }
    Xp[((size_t)(oy + 1) * 130 + ox + 1) * 64 + c] = (__hip_bfloat16)(acc * 0.25f);
}

// ---------------------------------------------------------------------------
// K6/K7: 3x3 conv + bias + ELU as 9-offset implicit MFMA GEMM.
// ---------------------------------------------------------------------------
template <int MODE>
__global__ __launch_bounds__(256) void convMfma(const __hip_bfloat16* __restrict__ Xp,
                                                const __hip_bfloat16* __restrict__ Wc,
                                                const float* __restrict__ Bi,
                                                __hip_bfloat16* __restrict__ Yp,
                                                float* __restrict__ Yo) {
    int tid = threadIdx.x, lane = tid & 63, w = tid >> 6;
    int y = blockIdx.x >> 1, x0 = (blockIdx.x & 1) * 64;
    int co0 = w * 16;
    int fl = lane & 15, fh = lane >> 4;

    bf16x8 wb[3][3][2];
    #pragma unroll
    for (int ky = 0; ky < 3; ++ky)
        #pragma unroll
        for (int kx = 0; kx < 3; ++kx)
            #pragma unroll
            for (int kc = 0; kc < 2; ++kc)
                wb[ky][kx][kc] = *(const bf16x8*)&Wc[(size_t)((ky * 3 + kx) * 64 + co0 + fl) * 64 + kc * 32 + fh * 8];

    f32x4 acc[4] = {};
    #pragma unroll
    for (int ky = 0; ky < 3; ++ky) {
        #pragma unroll
        for (int kx = 0; kx < 3; ++kx) {
            const __hip_bfloat16* xrow = Xp + ((size_t)(y + ky) * 130 + x0 + kx) * 64;
            #pragma unroll
            for (int kc = 0; kc < 2; ++kc) {
                #pragma unroll
                for (int mt = 0; mt < 4; ++mt) {
                    bf16x8 af = *(const bf16x8*)&xrow[(mt * 16 + fl) * 64 + kc * 32 + fh * 8];
                    acc[mt] = __builtin_amdgcn_mfma_f32_16x16x32_bf16(af, wb[ky][kx][kc], acc[mt], 0, 0, 0);
                }
            }
        }
    }

    float bias = Bi[co0 + fl];
    #pragma unroll
    for (int mt = 0; mt < 4; ++mt) {
        int xb = x0 + mt * 16 + fh * 4;
        if (MODE == 0) {
            #pragma unroll
            for (int r = 0; r < 4; ++r) {
                float v = acc[mt][r] + bias;
                v = v > 0.f ? v : expm1f(v);
                Yp[((size_t)(y + 1) * 130 + xb + r + 1) * 64 + co0 + fl] = (__hip_bfloat16)v;
            }
        } else {
            float4 o;
            float* op = (float*)&o;
            #pragma unroll
            for (int r = 0; r < 4; ++r) {
                float v = acc[mt][r] + bias;
                op[r] = v > 0.f ? v : expm1f(v);
            }
            *(float4*)&Yo[(size_t)(co0 + fl) * 16384 + y * 128 + xb] = o;
        }
    }
}

// ---------------------------------------------------------------------------
extern "C" void kernel_launch(void* const* d_in, const int* in_sizes, int n_in,
                              void* d_out, int out_size, void* d_ws, size_t ws_size,
                              hipStream_t stream) {
    const float* raw_w  = (const float*)d_in[0];
    const float* mm     = (const float*)d_in[1];
    const float* scores = (const float*)d_in[2];
    const float* w1     = (const float*)d_in[3];
    const float* b1     = (const float*)d_in[4];
    const float* w2     = (const float*)d_in[5];
    const float* b2     = (const float*)d_in[6];
    float* out = (float*)d_out;

    char* ws = (char*)d_ws;
    // Workspace map (live ranges verified disjoint):
    //  [0,32)   Pt                  [32,40)  Wt
    //  [41.25,41.5) Wc1,Wc2         [42,50) Mo q0 (fp16)  [50,58) Mo2
    //  [58,60.1) Xp                 [61,63.1) Y1p
    //  [64,128) Ft fp32 [q][l] (dead after rowSoftmax) -> Mo3@64, Mo4@72
    __hip_bfloat16* Pt  = (__hip_bfloat16*)ws;                    // 32 MiB
    __hip_bfloat16* Wt  = (__hip_bfloat16*)(ws + (32ull << 20));  // 8 MiB
    __hip_bfloat16* Wc1 = (__hip_bfloat16*)(ws + (41ull << 20) + (256u << 10));  // 72 KiB
    __hip_bfloat16* Wc2 = (__hip_bfloat16*)(ws + (41ull << 20) + (384u << 10));  // 72 KiB
    __half*         Mo  = (__half*)(ws + (42ull << 20));          // 8 MiB
    __half*         Mo2 = (__half*)(ws + (50ull << 20));          // 8 MiB
    __hip_bfloat16* Xp  = (__hip_bfloat16*)(ws + (58ull << 20));  // 2.07 MiB
    __hip_bfloat16* Y1p = (__hip_bfloat16*)(ws + (61ull << 20));  // 2.07 MiB
    float*          Ft  = (float*)(ws + (64ull << 20));           // 64 MiB
    __half*         Mo3 = (__half*)(ws + (64ull << 20));          // 8 MiB (aliases dead Ft)
    __half*         Mo4 = (__half*)(ws + (72ull << 20));          // 8 MiB

    fuseDT<<<dim3(256, 4), 256, 0, stream>>>(scores, Ft);
    transW<<<dim3(16, 64), 256, 0, stream>>>(raw_w, Wt);
    transWc<<<144, 256, 0, stream>>>(w1, Wc1);
    transWc<<<144, 256, 0, stream>>>(w2, Wc2);
    zeroB<<<516, 64, 0, stream>>>(Xp, Y1p);
    rowSoftmax<<<4096, 256, 0, stream>>>(Ft, mm, Pt);
    gemmMfmaK<<<1024, 256, 0, stream>>>(Pt, Wt, Mo, Mo2, Mo3, Mo4);  // Ft dead
    scatterD<<<4096, 256, 0, stream>>>(Mo, Mo2, Mo3, Mo4, Xp);
    convMfma<0><<<256, 256, 0, stream>>>(Xp, Wc1, b1, Y1p, nullptr);
    convMfma<1><<<256, 256, 0, stream>>>(Y1p, Wc2, b2, nullptr, out);
}

// Round 17
// 164.494 us; speedup vs baseline: 1.0552x; 1.0552x over previous
//
#include <hip/hip_runtime.h>
#include <hip/hip_bf16.h>
#include <hip/hip_fp16.h>
#include <math.h>

// Problem constants
#define NL 4096     // L patches
#define NQ 4096     // HS*WS pixels
#define SCALE 10.0f

typedef __bf16 bf16x8 __attribute__((ext_vector_type(8)));
typedef float  f32x4  __attribute__((ext_vector_type(4)));
typedef float  f32x4u __attribute__((ext_vector_type(4), aligned(4)));  // 4B-aligned vec load

#define GLOAD_LDS16(gp, lp)                                                        \
    __builtin_amdgcn_global_load_lds((const __attribute__((address_space(1))) void*)(gp), \
                                     (__attribute__((address_space(3))) void*)(lp), \
                                     16, 0, 0)

// ---------------------------------------------------------------------------
// K1: fused double-diagonal pass — round-13/15 config (measured best 56.3us;
// 6 structural variants all >= this; latency-bound equilibrium).
// ---------------------------------------------------------------------------
__global__ __launch_bounds__(256) void fuseD(const float* __restrict__ S,
                                             float* __restrict__ F) {
    int lin = blockIdx.x;
    int blk = (lin & 7) * 128 + (lin >> 3);   // bijective XCD chunking (1024%8==0)
    int l0 = blk * 4;
    int hb = l0 >> 6, wb0 = l0 & 63;          // wb0 in {0,4,...,60}
    int tid = threadIdx.x, lane = tid & 63;

    int rowbase[3]; float wm[3][4];
    #pragma unroll
    for (int d = 0; d < 3; ++d) {
        int h2 = hb + d - 1;
        #pragma unroll
        for (int i = 0; i < 4; ++i) wm[d][i] = 1.f;
        if (h2 >= 0 && h2 <= 63) rowbase[d] = h2 * 64 + wb0;
        else if (h2 < 0) {
            rowbase[d] = 4031 + wb0;
            #pragma unroll
            for (int i = 0; i < 4; ++i) wm[d][i] = (wb0 + i >= 1) ? 1.f : 0.f;
        } else {
            rowbase[d] = 1 + wb0;
            #pragma unroll
            for (int i = 0; i < 4; ++i) wm[d][i] = (wb0 + i <= 62) ? 1.f : 0.f;
        }
    }

    for (int cc = 0; cc < 4; ++cc) {
        int q0 = (cc * 256 + tid) * 4;
        int hs = q0 >> 6, ws0 = q0 & 63;
        f32x4 z4 = {0.f, 0.f, 0.f, 0.f};
        f32x4 acc0 = z4, acc1 = z4, acc2 = z4, acc3 = z4;

        #pragma unroll
        for (int d = 0; d < 3; ++d) {
            int s2 = hs + d - 1;
            bool cw = (s2 < 0) || (s2 > 63);
            int colb = cw ? ((s2 < 0 ? 4031 : 1) + ws0) : (q0 + (d - 1) * 64);
            int cb = cw ? colb - 1 : colb;

            f32x4 v[6], v2[6];
            #pragma unroll
            for (int r = 0; r < 6; ++r) {
                int rr = rowbase[d] - 1 + r;
                v[r] = z4;
                if (rr >= 0 && rr < 4096)
                    v[r] = *(const f32x4u*)(S + (size_t)rr * 4096 + cb);
            }
            if (cw) {
                #pragma unroll
                for (int r = 0; r < 6; ++r) {
                    int rr = rowbase[d] - 1 + r;
                    v2[r] = z4;
                    if (rr >= 0 && rr < 4096)
                        v2[r] = *(const f32x4u*)(S + (size_t)rr * 4096 + colb + 1);
                }
            }

            float lm[4], rm[4];
            #pragma unroll
            for (int r = 0; r < 4; ++r) lm[r] = __shfl_up(v[r][3], 1);
            #pragma unroll
            for (int r = 0; r < 4; ++r) rm[r] = __shfl_down(v[r + 2][0], 1);
            if (!cw) {
                if (lane == 0 || colb == 0) {
                    #pragma unroll
                    for (int r = 0; r < 4; ++r) {
                        int rr = rowbase[d] - 1 + r;
                        lm[r] = (colb > 0 && rr >= 0 && rr < 4096)
                                ? S[(size_t)rr * 4096 + colb - 1] : 0.f;
                    }
                }
                if (lane == 63 || colb + 4 >= 4096) {
                    #pragma unroll
                    for (int r = 0; r < 4; ++r) {
                        int rr = rowbase[d] + 1 + r;
                        rm[r] = (colb + 4 < 4096 && rr >= 0 && rr < 4096)
                                ? S[(size_t)rr * 4096 + colb + 4] : 0.f;
                    }
                }
            }

            f32x4 t[4];
            if (!cw) {
                #pragma unroll
                for (int i = 0; i < 4; ++i) {
                    f32x4 Lv = { lm[i], v[i][0], v[i][1], v[i][2] };
                    f32x4 Cv = v[i + 1];
                    f32x4 Rv = { v[i + 2][1], v[i + 2][2], v[i + 2][3], rm[i] };
                    t[i] = Lv + Cv + Rv;
                }
            } else {
                #pragma unroll
                for (int i = 0; i < 4; ++i) {
                    f32x4 Lv = v[i];
                    f32x4 Cv = { v[i+1][1], v[i+1][2], v[i+1][3], v2[i+1][2] };
                    f32x4 Rv = v2[i + 2];
                    t[i] = Lv + Cv + Rv;
                }
                if (s2 < 0 && ws0 == 0) { t[0][0] = 0.f; t[1][0] = 0.f; t[2][0] = 0.f; t[3][0] = 0.f; }
                if (s2 > 63 && ws0 == 60) { t[0][3] = 0.f; t[1][3] = 0.f; t[2][3] = 0.f; t[3][3] = 0.f; }
            }
            acc0 += wm[d][0] * t[0];
            acc1 += wm[d][1] * t[1];
            acc2 += wm[d][2] * t[2];
            acc3 += wm[d][3] * t[3];
        }
        *(f32x4*)(F + (size_t)(l0 + 0) * 4096 + q0) = acc0;
        *(f32x4*)(F + (size_t)(l0 + 1) * 4096 + q0) = acc1;
        *(f32x4*)(F + (size_t)(l0 + 2) * 4096 + q0) = acc2;
        *(f32x4*)(F + (size_t)(l0 + 3) * 4096 + q0) = acc3;
    }
}

// ---------------------------------------------------------------------------
// S1: partial softmax stats on F[l][q] (column softmax).
// ---------------------------------------------------------------------------
__global__ __launch_bounds__(256) void softPart(const float* __restrict__ F,
                                                const float* __restrict__ mm,
                                                float* __restrict__ Pm,
                                                float* __restrict__ Ps) {
    int qt = blockIdx.x, lc = blockIdx.y;
    int qo = threadIdx.x & 63, lg = threadIdx.x >> 6;
    int q = qt * 64 + qo;
    __shared__ float red[4][64];

    float sv[32];
    float m = -1e30f;
    #pragma unroll
    for (int i = 0; i < 32; ++i) {
        int l = lc * 128 + i * 4 + lg;
        float s = F[(size_t)l * 4096 + q] * mm[l] * SCALE;
        sv[i] = s;
        m = fmaxf(m, s);
    }
    red[lg][qo] = m;
    __syncthreads();
    m = fmaxf(fmaxf(red[0][qo], red[1][qo]), fmaxf(red[2][qo], red[3][qo]));
    __syncthreads();

    float sum = 0.f;
    #pragma unroll
    for (int i = 0; i < 32; ++i) sum += __expf(sv[i] - m);
    red[lg][qo] = sum;
    __syncthreads();
    if (lg == 0) {
        sum = red[0][qo] + red[1][qo] + red[2][qo] + red[3][qo];
        Pm[lc * 4096 + q] = m;
        Ps[lc * 4096 + q] = sum;
    }
}

// ---------------------------------------------------------------------------
// S2: combine 32 chunk partials per q.
// ---------------------------------------------------------------------------
__global__ void softComb(const float* __restrict__ Pm, const float* __restrict__ Ps,
                         float* __restrict__ Qm, float* __restrict__ Qi) {
    int q = blockIdx.x * 256 + threadIdx.x;
    float M = -1e30f;
    #pragma unroll
    for (int i = 0; i < 32; ++i) M = fmaxf(M, Pm[i * 4096 + q]);
    float S = 0.f;
    #pragma unroll
    for (int i = 0; i < 32; ++i) S += Ps[i * 4096 + q] * __expf(Pm[i * 4096 + q] - M);
    Qm[q] = M;
    Qi[q] = 1.0f / S;
}

// ---------------------------------------------------------------------------
// S3: normalize + bf16 convert + transpose (vectorized, round-15 verified).
// ---------------------------------------------------------------------------
__global__ __launch_bounds__(256) void normTransP(const float* __restrict__ F,
                                                  const float* __restrict__ mm,
                                                  const float* __restrict__ Qm,
                                                  const float* __restrict__ Qi,
                                                  __hip_bfloat16* __restrict__ Pt) {
    __shared__ float T[64][65];
    int qt = blockIdx.x, lt = blockIdx.y;
    int t = threadIdx.x;
    int lq = t >> 4;              // 0..15
    int q4 = (t & 15) * 4;        // 0..60
    float4 qm4 = *(const float4*)&Qm[qt * 64 + q4];
    float4 qi4 = *(const float4*)&Qi[qt * 64 + q4];

    #pragma unroll
    for (int p = 0; p < 4; ++p) {
        int l = p * 16 + lq;
        float mml = mm[lt * 64 + l];
        f32x4 v = *(const f32x4*)&F[(size_t)(lt * 64 + l) * 4096 + qt * 64 + q4];
        T[l][q4 + 0] = mml * __expf(v[0] * mml * SCALE - qm4.x) * qi4.x;
        T[l][q4 + 1] = mml * __expf(v[1] * mml * SCALE - qm4.y) * qi4.y;
        T[l][q4 + 2] = mml * __expf(v[2] * mml * SCALE - qm4.z) * qi4.z;
        T[l][q4 + 3] = mml * __expf(v[3] * mml * SCALE - qm4.w) * qi4.w;
    }
    __syncthreads();

    int l4 = (t & 15) * 4;
    #pragma unroll
    for (int p = 0; p < 4; ++p) {
        int ql = p * 16 + (t >> 4);
        __hip_bfloat16 ob[4];
        #pragma unroll
        for (int i = 0; i < 4; ++i) ob[i] = (__hip_bfloat16)T[l4 + i][ql];
        *(uint2*)&Pt[(size_t)(qt * 64 + ql) * 4096 + lt * 64 + l4] = *(const uint2*)ob;
    }
}

// ---------------------------------------------------------------------------
// Wt: transpose + convert raw_w [k][ck] fp32 -> Wt [n][k] bf16, N permuted
// as n = kyx*64 + c (so scatterD reads Mo coalesced).
// ---------------------------------------------------------------------------
__global__ __launch_bounds__(256) void transW(const float* __restrict__ Wsrc,
                                              __hip_bfloat16* __restrict__ Wt) {
    __shared__ float T[64][65];
    int nt = blockIdx.x, kt = blockIdx.y;
    int c = threadIdx.x & 63;
    #pragma unroll
    for (int p = 0; p < 16; ++p) {
        int r = p * 4 + (threadIdx.x >> 6);
        T[r][c] = Wsrc[(size_t)(kt * 64 + r) * 1024 + nt * 64 + c];
    }
    __syncthreads();
    #pragma unroll
    for (int p = 0; p < 16; ++p) {
        int r = p * 4 + (threadIdx.x >> 6);   // r = ck_local; ck = nt*64 + r
        int n_new = (r & 15) * 64 + nt * 4 + (r >> 4);   // kyx*64 + c_chan
        Wt[(size_t)n_new * 4096 + kt * 64 + c] = (__hip_bfloat16)T[c][r];
    }
}

// ---------------------------------------------------------------------------
// Wc prep: conv weight [co][ci][3][3] fp32 -> Wc[kyx][co][ci] bf16.
// ---------------------------------------------------------------------------
__global__ void transWc(const float* __restrict__ Wsrc, __hip_bfloat16* __restrict__ Wd) {
    int t = blockIdx.x * 256 + threadIdx.x;   // kyx*4096 + co*64 + ci
    int kyx = t >> 12;
    int co = (t >> 6) & 63;
    int ci = t & 63;
    Wd[t] = (__hip_bfloat16)Wsrc[co * 576 + ci * 9 + kyx];
}

// ---------------------------------------------------------------------------
// zeroB: zero only the borders of padded NHWC buffers Xp and Y1p (replaces
// the two 2MB memsets; interiors fully written by scatterD / convMfma<0>;
// validated in the passing round-16 run).
// ---------------------------------------------------------------------------
__global__ void zeroB(__hip_bfloat16* __restrict__ Xp, __hip_bfloat16* __restrict__ Y1p) {
    int p = blockIdx.x;        // 0..515 border pixel index
    int c = threadIdx.x;       // 0..63
    int y, x;
    if (p < 130)      { y = 0;   x = p; }
    else if (p < 260) { y = 129; x = p - 130; }
    else if (p < 388) { y = p - 260 + 1; x = 0; }
    else              { y = p - 388 + 1; x = 129; }
    size_t off = ((size_t)y * 130 + x) * 64 + c;
    Xp[off]  = (__hip_bfloat16)0.f;
    Y1p[off] = (__hip_bfloat16)0.f;
}

// ---------------------------------------------------------------------------
// K4: bf16 MFMA GEMM, K-SPLIT x4, fp16 C quarters. Grid 1024 = 4 blocks/CU;
// bn fastest within XCD chunk; both-sides XOR swizzle (conflicts=0 verified).
// ~860 GF = at the 128^2-structure plain-HIP ceiling.
// ---------------------------------------------------------------------------
__global__ __launch_bounds__(256) void gemmMfmaK(const __hip_bfloat16* __restrict__ Ab,
                                                 const __hip_bfloat16* __restrict__ Bb,
                                                 __half* __restrict__ C0,
                                                 __half* __restrict__ C1,
                                                 __half* __restrict__ C2,
                                                 __half* __restrict__ C3) {
    __shared__ __align__(16) __hip_bfloat16 As[2][128][32];  // 16 KiB
    __shared__ __align__(16) __hip_bfloat16 Bs[2][128][32];  // 16 KiB
    int lin = blockIdx.x;
    int wid = (lin & 7) * 128 + (lin >> 3);   // bijective XCD chunking (1024%8==0)
    int bz = wid >> 8;                         // 0..3 K-quarter
    int r5 = wid & 255;
    int bn = r5 & 7;                           // bn fastest -> B-panel L2 reuse
    int bm = r5 >> 3;
    int bm0 = bm * 128, bn0 = bn * 128;
    size_t kbase = (size_t)bz * 1024;
    __half* Cm = (bz == 0) ? C0 : (bz == 1) ? C1 : (bz == 2) ? C2 : C3;

    int tid = threadIdx.x;
    int lane = tid & 63, w = tid >> 6;
    int wm = (w >> 1) * 64, wn = (w & 1) * 64;

    int srow = w * 32 + (lane >> 2);
    int scol = (((lane & 3) ^ ((lane >> 3) & 3))) * 8;   // swizzled source col
    const __hip_bfloat16* ga0 = Ab + (size_t)(bm0 + srow) * 4096 + kbase + scol;
    const __hip_bfloat16* ga1 = Ab + (size_t)(bm0 + srow + 16) * 4096 + kbase + scol;
    const __hip_bfloat16* gb0 = Bb + (size_t)(bn0 + srow) * 4096 + kbase + scol;
    const __hip_bfloat16* gb1 = Bb + (size_t)(bn0 + srow + 16) * 4096 + kbase + scol;

    f32x4 acc[4][4] = {};
    int fm = lane & 15;
    int fkz = (((lane >> 4) ^ ((lane >> 1) & 3))) * 8;   // swizzled k-offset

    GLOAD_LDS16(ga0, &As[0][w * 32][0]);
    GLOAD_LDS16(ga1, &As[0][w * 32 + 16][0]);
    GLOAD_LDS16(gb0, &Bs[0][w * 32][0]);
    GLOAD_LDS16(gb1, &Bs[0][w * 32 + 16][0]);
    __syncthreads();

    int buf = 0;
    for (int t = 0; t < 32; ++t) {
        if (t + 1 < 32) {
            int k0 = (t + 1) * 32;
            GLOAD_LDS16(ga0 + k0, &As[buf ^ 1][w * 32][0]);
            GLOAD_LDS16(ga1 + k0, &As[buf ^ 1][w * 32 + 16][0]);
            GLOAD_LDS16(gb0 + k0, &Bs[buf ^ 1][w * 32][0]);
            GLOAD_LDS16(gb1 + k0, &Bs[buf ^ 1][w * 32 + 16][0]);
        }
        bf16x8 af[4], bfr[4];
        #pragma unroll
        for (int i = 0; i < 4; ++i)
            af[i] = *(const bf16x8*)&As[buf][wm + i * 16 + fm][fkz];
        #pragma unroll
        for (int j = 0; j < 4; ++j)
            bfr[j] = *(const bf16x8*)&Bs[buf][wn + j * 16 + fm][fkz];
        #pragma unroll
        for (int i = 0; i < 4; ++i)
            #pragma unroll
            for (int j = 0; j < 4; ++j)
                acc[i][j] = __builtin_amdgcn_mfma_f32_16x16x32_bf16(af[i], bfr[j], acc[i][j], 0, 0, 0);
        __syncthreads();
        buf ^= 1;
    }

    // D mapping: col = lane&15, row = (lane>>4)*4 + reg  [HW-verified]
    #pragma unroll
    for (int i = 0; i < 4; ++i) {
        #pragma unroll
        for (int j = 0; j < 4; ++j) {
            int row = bm0 + wm + i * 16 + (lane >> 4) * 4;
            int col = bn0 + wn + j * 16 + (lane & 15);
            #pragma unroll
            for (int r = 0; r < 4; ++r)
                Cm[(size_t)(row + r) * 1024 + col] = __float2half(acc[i][j][r]);
        }
    }
}

// ---------------------------------------------------------------------------
// K5: transposed-conv gather + /4, summing the four fp16 K-quarters ->
// padded NHWC bf16 Xp[130][130][64] (interior only; borders via zeroB).
// ---------------------------------------------------------------------------
__global__ void scatterD(const __half* __restrict__ Mo, const __half* __restrict__ Mo2,
                         const __half* __restrict__ Mo3, const __half* __restrict__ Mo4,
                         __hip_bfloat16* __restrict__ Xp) {
    int c = threadIdx.x & 63;
    int pix = blockIdx.x * 4 + (threadIdx.x >> 6);
    int ox = pix & 127, oy = pix >> 7;
    float acc = 0.f;
    #pragma unroll
    for (int ky = 0; ky < 4; ++ky) {
        int ty = oy + 1 - ky;
        if (ty & 1) continue;
        int iy = ty >> 1;
        if (iy < 0 || iy >= 64) continue;
        #pragma unroll
        for (int kx = 0; kx < 4; ++kx) {
            int txx = ox + 1 - kx;
            if (txx & 1) continue;
            int ix = txx >> 1;
            if (ix < 0 || ix >= 64) continue;
            size_t off = (size_t)(iy * 64 + ix) * 1024 + (ky * 4 + kx) * 64 + c;
            acc += (__half2float(Mo[off]) + __half2float(Mo2[off]))
                 + (__half2float(Mo3[off]) + __half2float(Mo4[off]));
        }
    }
    Xp[((size_t)(oy + 1) * 130 + ox + 1) * 64 + c] = (__hip_bfloat16)(acc * 0.25f);
}

// ---------------------------------------------------------------------------
// K6/K7: 3x3 conv + bias + ELU as 9-offset implicit MFMA GEMM.
// ---------------------------------------------------------------------------
template <int MODE>
__global__ __launch_bounds__(256) void convMfma(const __hip_bfloat16* __restrict__ Xp,
                                                const __hip_bfloat16* __restrict__ Wc,
                                                const float* __restrict__ Bi,
                                                __hip_bfloat16* __restrict__ Yp,
                                                float* __restrict__ Yo) {
    int tid = threadIdx.x, lane = tid & 63, w = tid >> 6;
    int y = blockIdx.x >> 1, x0 = (blockIdx.x & 1) * 64;
    int co0 = w * 16;
    int fl = lane & 15, fh = lane >> 4;

    bf16x8 wb[3][3][2];
    #pragma unroll
    for (int ky = 0; ky < 3; ++ky)
        #pragma unroll
        for (int kx = 0; kx < 3; ++kx)
            #pragma unroll
            for (int kc = 0; kc < 2; ++kc)
                wb[ky][kx][kc] = *(const bf16x8*)&Wc[(size_t)((ky * 3 + kx) * 64 + co0 + fl) * 64 + kc * 32 + fh * 8];

    f32x4 acc[4] = {};
    #pragma unroll
    for (int ky = 0; ky < 3; ++ky) {
        #pragma unroll
        for (int kx = 0; kx < 3; ++kx) {
            const __hip_bfloat16* xrow = Xp + ((size_t)(y + ky) * 130 + x0 + kx) * 64;
            #pragma unroll
            for (int kc = 0; kc < 2; ++kc) {
                #pragma unroll
                for (int mt = 0; mt < 4; ++mt) {
                    bf16x8 af = *(const bf16x8*)&xrow[(mt * 16 + fl) * 64 + kc * 32 + fh * 8];
                    acc[mt] = __builtin_amdgcn_mfma_f32_16x16x32_bf16(af, wb[ky][kx][kc], acc[mt], 0, 0, 0);
                }
            }
        }
    }

    float bias = Bi[co0 + fl];
    #pragma unroll
    for (int mt = 0; mt < 4; ++mt) {
        int xb = x0 + mt * 16 + fh * 4;
        if (MODE == 0) {
            #pragma unroll
            for (int r = 0; r < 4; ++r) {
                float v = acc[mt][r] + bias;
                v = v > 0.f ? v : expm1f(v);
                Yp[((size_t)(y + 1) * 130 + xb + r + 1) * 64 + co0 + fl] = (__hip_bfloat16)v;
            }
        } else {
            float4 o;
            float* op = (float*)&o;
            #pragma unroll
            for (int r = 0; r < 4; ++r) {
                float v = acc[mt][r] + bias;
                op[r] = v > 0.f ? v : expm1f(v);
            }
            *(float4*)&Yo[(size_t)(co0 + fl) * 16384 + y * 128 + xb] = o;
        }
    }
}

// ---------------------------------------------------------------------------
extern "C" void kernel_launch(void* const* d_in, const int* in_sizes, int n_in,
                              void* d_out, int out_size, void* d_ws, size_t ws_size,
                              hipStream_t stream) {
    const float* raw_w  = (const float*)d_in[0];
    const float* mm     = (const float*)d_in[1];
    const float* scores = (const float*)d_in[2];
    const float* w1     = (const float*)d_in[3];
    const float* b1     = (const float*)d_in[4];
    const float* w2     = (const float*)d_in[5];
    const float* b2     = (const float*)d_in[6];
    float* out = (float*)d_out;

    char* ws = (char*)d_ws;
    // Workspace map (live ranges verified disjoint):
    //  [0,32)   Pt                  [32,40)  Wt
    //  [40,41)  Pm+Ps               [41,41.06) Qm,Qi
    //  [41.25,41.5) Wc1,Wc2         [42,50) Mo q0 (fp16)  [50,58) Mo2
    //  [58,60.1) Xp                 [61,63.1) Y1p
    //  [64,128) F (dead after normTransP) -> Mo3@64, Mo4@72 (fp16 quarters)
    __hip_bfloat16* Pt  = (__hip_bfloat16*)ws;                    // 32 MiB
    __hip_bfloat16* Wt  = (__hip_bfloat16*)(ws + (32ull << 20));  // 8 MiB
    float*          Pm  = (float*)(ws + (40ull << 20));           // 512 KiB
    float*          Ps  = (float*)(ws + (40ull << 20) + (512u << 10));
    float*          Qm  = (float*)(ws + (41ull << 20));           // 16 KiB
    float*          Qi  = (float*)(ws + (41ull << 20) + (64u << 10));
    __hip_bfloat16* Wc1 = (__hip_bfloat16*)(ws + (41ull << 20) + (256u << 10));  // 72 KiB
    __hip_bfloat16* Wc2 = (__hip_bfloat16*)(ws + (41ull << 20) + (384u << 10));  // 72 KiB
    __half*         Mo  = (__half*)(ws + (42ull << 20));          // 8 MiB
    __half*         Mo2 = (__half*)(ws + (50ull << 20));          // 8 MiB
    __hip_bfloat16* Xp  = (__hip_bfloat16*)(ws + (58ull << 20));  // 2.07 MiB
    __hip_bfloat16* Y1p = (__hip_bfloat16*)(ws + (61ull << 20));  // 2.07 MiB
    float*          F   = (float*)(ws + (64ull << 20));           // 64 MiB
    __half*         Mo3 = (__half*)(ws + (64ull << 20));          // 8 MiB (aliases dead F)
    __half*         Mo4 = (__half*)(ws + (72ull << 20));          // 8 MiB

    fuseD<<<1024, 256, 0, stream>>>(scores, F);
    transW<<<dim3(16, 64), 256, 0, stream>>>(raw_w, Wt);
    transWc<<<144, 256, 0, stream>>>(w1, Wc1);
    transWc<<<144, 256, 0, stream>>>(w2, Wc2);
    zeroB<<<516, 64, 0, stream>>>(Xp, Y1p);
    softPart<<<dim3(64, 32), 256, 0, stream>>>(F, mm, Pm, Ps);
    softComb<<<16, 256, 0, stream>>>(Pm, Ps, Qm, Qi);
    normTransP<<<dim3(64, 64), 256, 0, stream>>>(F, mm, Qm, Qi, Pt);
    gemmMfmaK<<<1024, 256, 0, stream>>>(Pt, Wt, Mo, Mo2, Mo3, Mo4);  // F dead
    scatterD<<<4096, 256, 0, stream>>>(Mo, Mo2, Mo3, Mo4, Xp);
    convMfma<0><<<256, 256, 0, stream>>>(Xp, Wc1, b1, Y1p, nullptr);
    convMfma<1><<<256, 256, 0, stream>>>(Y1p, Wc2, b2, nullptr, out);
}